// Round 16
// baseline (367.017 us; speedup 1.0000x reference)
//
#include <hip/hip_runtime.h>
#include <stdint.h>
#include <stddef.h>

// Problem constants
#define B_    16
#define N_SEQ 4096
#define C_    512
#define H_    8
#define E_    64
#define M_TOT (B_ * N_SEQ)   // 65536
#define QKVN  (3 * C_)       // 1536

typedef __attribute__((ext_vector_type(8))) short short8;
typedef __attribute__((ext_vector_type(4))) short s16x4;
typedef __attribute__((ext_vector_type(4))) float f32x4;

__device__ __forceinline__ unsigned short f2bf(float f) {
  uint32_t u = __builtin_bit_cast(uint32_t, f);
  return (unsigned short)((u + 0x7fffu + ((u >> 16) & 1u)) >> 16);  // RNE
}
__device__ __forceinline__ float bf2f(unsigned short h) {
  uint32_t u = ((uint32_t)h) << 16;
  return __builtin_bit_cast(float, u);
}

// ---------------------------------------------------------------- weight cvt + zero (one small dispatch)
// blocks [0,384): W_qkv f32->bf16; [384,512): W_proj; [512,1032): zero KVT+ksum
__global__ __launch_bounds__(256) void cvt_w(const float* __restrict__ wq,
                                             const float* __restrict__ wp,
                                             unsigned short* __restrict__ wqo,
                                             unsigned short* __restrict__ wpo,
                                             float* __restrict__ zbuf) {
  const int bb = blockIdx.x;
  if (bb >= 512) {
    size_t i = ((size_t)(bb - 512) * 256 + threadIdx.x) * 4;
    *(float4*)(zbuf + i) = make_float4(0.f, 0.f, 0.f, 0.f);
    return;
  }
  const float* in;
  unsigned short* out;
  size_t base;
  if (bb < 384) { in = wq; out = wqo; base = (size_t)bb * 2048; }
  else          { in = wp; out = wpo; base = (size_t)(bb - 384) * 2048; }
  size_t i = base + (size_t)threadIdx.x * 8;
  float4 a = *(const float4*)(in + i);
  float4 b = *(const float4*)(in + i + 4);
  short8 o;
  o[0] = (short)f2bf(a.x); o[1] = (short)f2bf(a.y);
  o[2] = (short)f2bf(a.z); o[3] = (short)f2bf(a.w);
  o[4] = (short)f2bf(b.x); o[5] = (short)f2bf(b.y);
  o[6] = (short)f2bf(b.z); o[7] = (short)f2bf(b.w);
  *(short8*)(out + i) = o;
}

#define GLD16(g, l)                                                              \
  __builtin_amdgcn_global_load_lds(                                              \
      (const __attribute__((address_space(1))) void*)(g),                        \
      (__attribute__((address_space(3))) void*)(l), 16, 0, 0)

// ---------------------------------------------------------------- GEMM1: qkv = x(f32) * Wqkv^T
// R12's verified 256x256/BK=64/8-wave/slot-XOR structure, with A reg-staged
// directly from f32 x (fuses away the 201 MB x-conversion pass):
//  - LOADA(kt+1) issued at top of iteration kt (8x float4; 16 lanes cover one
//    row's 256B contiguously -> 4x256B runs per instruction);
//  - MFMA phase hides the HBM latency (T14 issue-early/write-late);
//  - WRITEA(kt+1) after MFMA: v_cvt_pk_bf16_f32 pairs -> ds_write_b64 into the
//    same swizzled layout (LDS slot s' holds global slot s'^(row&7));
//  - B stays on the verified global_load_lds path.
// Hazards: WRITEA(kt+1) targets buf[(kt+1)&1]; its last readers joined the
// barrier ending kt-1. End-of-kt __syncthreads drains ds_writes + B vmcnt.
__global__ __launch_bounds__(512, 2) void gemm_qkv(
    const float* __restrict__ Af, const unsigned short* __restrict__ Bm,
    unsigned short* __restrict__ Cq, float* __restrict__ ksum, int NT) {
  const int K = 512, N = QKVN;
  __shared__ unsigned short lds[2][2][256 * 64];  // 128 KiB
  const int q8 = gridDim.x >> 3;
  int bid = blockIdx.x;
  bid = (bid & 7) * q8 + (bid >> 3);
  const int mt = bid / NT, nt = bid - mt * NT;
  const int row0 = mt << 8, col0 = nt << 8;
  const int tid = threadIdx.x;
  const int lane = tid & 63, wave = tid >> 6;
  const int wm = wave & 1, wn = wave >> 1;
  const int fr = lane & 15, fg = lane >> 4;

  // B staging (R12-verified, pre-swizzled source)
  const int s_row = tid >> 3;
  const int s_slot = (tid & 7) ^ (s_row & 7);
  const unsigned short* gB = Bm + (size_t)(col0 + s_row) * K + s_slot * 8;

  // A f32 source: 16 lanes cover one row's 64 elems (256B); 8 row-passes
  const int a_sub = tid & 15;          // float4 index within row
  const int a_rbase = tid >> 4;        // row 0..31 (+32 per pass)
  const float* gAf = Af + (size_t)(row0 + a_rbase) * K + a_sub * 4;

  f32x4 acc[8][4] = {};
  float4 pf[8];

#define STAGE_B(kt)                                                      \
  {                                                                      \
    unsigned short* dB = &lds[(kt) & 1][1][tid * 8];                     \
    _Pragma("unroll")                                                    \
    for (int i = 0; i < 4; i++)                                          \
      GLD16(gB + (size_t)i * 64 * K + (kt) * 64, dB + i * 4096);         \
  }
#define LOADA(kt)                                                        \
  _Pragma("unroll")                                                      \
  for (int p = 0; p < 8; p++)                                            \
    pf[p] = *(const float4*)(gAf + (size_t)p * 32 * K + (kt) * 64);
#define WRITEA(kt)                                                       \
  {                                                                      \
    unsigned short* bufA = &lds[(kt) & 1][0][0];                         \
    _Pragma("unroll")                                                    \
    for (int p = 0; p < 8; p++) {                                        \
      const int row = a_rbase + p * 32;                                  \
      uint32_t lo, hi;                                                   \
      asm("v_cvt_pk_bf16_f32 %0, %1, %2" : "=v"(lo)                      \
          : "v"(pf[p].x), "v"(pf[p].y));                                 \
      asm("v_cvt_pk_bf16_f32 %0, %1, %2" : "=v"(hi)                      \
          : "v"(pf[p].z), "v"(pf[p].w));                                 \
      uint2 wv; wv.x = lo; wv.y = hi;                                    \
      *(uint2*)&bufA[row * 64 + (((a_sub >> 1) ^ (row & 7)) << 3) +      \
                     ((a_sub & 1) << 2)] = wv;                           \
    }                                                                    \
  }

  LOADA(0);
  STAGE_B(0);
  WRITEA(0);
  __syncthreads();

  for (int kt = 0; kt < 8; ++kt) {
    if (kt < 7) { LOADA(kt + 1); STAGE_B(kt + 1); }
    const unsigned short* bufA = &lds[kt & 1][0][0];
    const unsigned short* bufB = &lds[kt & 1][1][0];
#pragma unroll
    for (int kk = 0; kk < 2; ++kk) {
      const int sl = ((kk * 4 + fg) ^ (fr & 7)) * 8;
      short8 af[8], bg[4];
#pragma unroll
      for (int m = 0; m < 8; m++)
        af[m] = *(const short8*)&bufA[(wm * 128 + m * 16 + fr) * 64 + sl];
#pragma unroll
      for (int n = 0; n < 4; n++)
        bg[n] = *(const short8*)&bufB[(wn * 64 + n * 16 + fr) * 64 + sl];
      __builtin_amdgcn_s_setprio(1);
#pragma unroll
      for (int m = 0; m < 8; m++)
#pragma unroll
        for (int n = 0; n < 4; n++)
          acc[m][n] = __builtin_amdgcn_mfma_f32_16x16x32_bf16(af[m], bg[n], acc[m][n], 0, 0, 0);
      __builtin_amdgcn_s_setprio(0);
    }
    if (kt < 7) WRITEA(kt + 1);
    __syncthreads();   // drains A ds_writes + B vmcnt; joins readers of buf kt&1
  }
#undef STAGE_B
#undef LOADA
#undef WRITEA

  const bool isqk = (col0 < 2 * C_);
  const bool isk = (col0 >= C_) && (col0 < 2 * C_);
  float ksp[4] = {0.f, 0.f, 0.f, 0.f};
#pragma unroll
  for (int m = 0; m < 8; m++) {
    const int r0 = row0 + wm * 128 + m * 16 + fg * 4;
#pragma unroll
    for (int n = 0; n < 4; n++) {
      const int c = col0 + wn * 64 + n * 16 + fr;
#pragma unroll
      for (int r = 0; r < 4; r++) {
        float v = acc[m][n][r];
        if (isqk) v = fmaxf(v, 0.0f) + 0.125f;   // relu + E^-0.5
        if (isk) ksp[n] += v;
        Cq[(size_t)(r0 + r) * N + c] = f2bf(v);
      }
    }
  }
  if (isk) {
    const int b = row0 >> 12;
#pragma unroll
    for (int n = 0; n < 4; n++) {
      float s = ksp[n];
      s += __shfl_xor(s, 16, 64);
      s += __shfl_xor(s, 32, 64);
      if (lane < 16) {
        const int cc = col0 + wn * 64 + n * 16 + lane - C_;  // 0..511
        atomicAdd(&ksum[(size_t)((b << 3) + (cc >> 6)) * 64 + (cc & 63)], s);
      }
    }
  }
}

// ---------------------------------------------------------------- GEMM2 (R12-verified): out = hout * Wp^T + bias
__global__ __launch_bounds__(512, 2) void gemm_out(
    const unsigned short* __restrict__ A, const unsigned short* __restrict__ Bm,
    float* __restrict__ Cf, const float* __restrict__ bias, int NT) {
  const int K = 512, N = C_;
  __shared__ unsigned short lds[2][2][256 * 64];  // 128 KiB
  const int q8 = gridDim.x >> 3;
  int bid = blockIdx.x;
  bid = (bid & 7) * q8 + (bid >> 3);
  const int mt = bid / NT, nt = bid - mt * NT;
  const int row0 = mt << 8, col0 = nt << 8;
  const int tid = threadIdx.x;
  const int lane = tid & 63, wave = tid >> 6;
  const int wm = wave & 1, wn = wave >> 1;
  const int fr = lane & 15, fg = lane >> 4;

  const int s_row = tid >> 3;
  const int s_slot = (tid & 7) ^ (s_row & 7);
  const unsigned short* gA = A + (size_t)(row0 + s_row) * K + s_slot * 8;
  const unsigned short* gB = Bm + (size_t)(col0 + s_row) * K + s_slot * 8;

  f32x4 acc[8][4] = {};

#define STAGE(kt)                                                        \
  {                                                                      \
    unsigned short* dA = &lds[(kt) & 1][0][tid * 8];                     \
    unsigned short* dB = &lds[(kt) & 1][1][tid * 8];                     \
    _Pragma("unroll")                                                    \
    for (int i = 0; i < 4; i++) {                                        \
      GLD16(gA + (size_t)i * 64 * K + (kt) * 64, dA + i * 4096);         \
      GLD16(gB + (size_t)i * 64 * K + (kt) * 64, dB + i * 4096);         \
    }                                                                    \
  }

  STAGE(0);
  __syncthreads();

  for (int kt = 0; kt < 8; ++kt) {
    if (kt < 7) STAGE(kt + 1);
    const unsigned short* bufA = &lds[kt & 1][0][0];
    const unsigned short* bufB = &lds[kt & 1][1][0];
#pragma unroll
    for (int kk = 0; kk < 2; ++kk) {
      const int sl = ((kk * 4 + fg) ^ (fr & 7)) * 8;
      short8 af[8], bg[4];
#pragma unroll
      for (int m = 0; m < 8; m++)
        af[m] = *(const short8*)&bufA[(wm * 128 + m * 16 + fr) * 64 + sl];
#pragma unroll
      for (int n = 0; n < 4; n++)
        bg[n] = *(const short8*)&bufB[(wn * 64 + n * 16 + fr) * 64 + sl];
      __builtin_amdgcn_s_setprio(1);
#pragma unroll
      for (int m = 0; m < 8; m++)
#pragma unroll
        for (int n = 0; n < 4; n++)
          acc[m][n] = __builtin_amdgcn_mfma_f32_16x16x32_bf16(af[m], bg[n], acc[m][n], 0, 0, 0);
      __builtin_amdgcn_s_setprio(0);
    }
    __syncthreads();
  }
#undef STAGE

#pragma unroll
  for (int m = 0; m < 8; m++) {
    const int r0 = row0 + wm * 128 + m * 16 + fg * 4;
#pragma unroll
    for (int n = 0; n < 4; n++) {
      const int c = col0 + wn * 64 + n * 16 + fr;
      const float bb = bias[c];
#pragma unroll
      for (int r = 0; r < 4; r++)
        Cf[(size_t)(r0 + r) * N + c] = acc[m][n][r] + bb;
    }
  }
}

// ---------------------------------------------------------------- KV^T via MFMA (proven)
__global__ __launch_bounds__(256) void kv_mfma(const unsigned short* __restrict__ qkv,
                                               float* __restrict__ KVT) {
  const int bid = blockIdx.x;
  const int ch = bid & 7, bh = bid >> 3;
  const int h = bh & 7, b = bh >> 3;
  const int n0 = ch << 9;
  __shared__ unsigned short ktile[64][68];
  __shared__ unsigned short vtile[64][68];
  const int tid = threadIdx.x;
  const int lane = tid & 63, w = tid >> 6;
  const int fr = lane & 15, fg = lane >> 4;
  const int srow = tid >> 3;
  const int sseg = (tid & 7) << 3;
  const unsigned short* gk = qkv + (size_t)(b * N_SEQ + n0 + srow) * QKVN + C_ + h * E_ + sseg;
  const unsigned short* gv = gk + C_;

  f32x4 acc[4] = {};
  short8 pk0, pk1, pv0, pv1;
  pk0 = *(const short8*)gk;
  pk1 = *(const short8*)(gk + (size_t)32 * QKVN);
  pv0 = *(const short8*)gv;
  pv1 = *(const short8*)(gv + (size_t)32 * QKVN);

  for (int it = 0; it < 8; ++it) {
    {
      s16x4* dk0 = (s16x4*)&ktile[srow][sseg];
      s16x4* dk1 = (s16x4*)&ktile[srow + 32][sseg];
      s16x4* dv0 = (s16x4*)&vtile[srow][sseg];
      s16x4* dv1 = (s16x4*)&vtile[srow + 32][sseg];
      const s16x4* s;
      s = (const s16x4*)&pk0; dk0[0] = s[0]; dk0[1] = s[1];
      s = (const s16x4*)&pk1; dk1[0] = s[0]; dk1[1] = s[1];
      s = (const s16x4*)&pv0; dv0[0] = s[0]; dv0[1] = s[1];
      s = (const s16x4*)&pv1; dv1[0] = s[0]; dv1[1] = s[1];
    }
    __syncthreads();
    if (it < 7) {
      const unsigned short* nk = gk + (size_t)(it + 1) * 64 * QKVN;
      const unsigned short* nv = gv + (size_t)(it + 1) * 64 * QKVN;
      pk0 = *(const short8*)nk;
      pk1 = *(const short8*)(nk + (size_t)32 * QKVN);
      pv0 = *(const short8*)nv;
      pv1 = *(const short8*)(nv + (size_t)32 * QKVN);
    }
#pragma unroll
    for (int ks = 0; ks < 2; ++ks) {
      const int kb = ks * 32;
      short8 av, bk0, bk1, bk2, bk3;
#pragma unroll
      for (int j = 0; j < 8; ++j) {
        const int row = kb + fg * 8 + j;
        av[j]  = (short)vtile[row][w * 16 + fr];
        bk0[j] = (short)ktile[row][fr];
        bk1[j] = (short)ktile[row][16 + fr];
        bk2[j] = (short)ktile[row][32 + fr];
        bk3[j] = (short)ktile[row][48 + fr];
      }
      acc[0] = __builtin_amdgcn_mfma_f32_16x16x32_bf16(av, bk0, acc[0], 0, 0, 0);
      acc[1] = __builtin_amdgcn_mfma_f32_16x16x32_bf16(av, bk1, acc[1], 0, 0, 0);
      acc[2] = __builtin_amdgcn_mfma_f32_16x16x32_bf16(av, bk2, acc[2], 0, 0, 0);
      acc[3] = __builtin_amdgcn_mfma_f32_16x16x32_bf16(av, bk3, acc[3], 0, 0, 0);
    }
    __syncthreads();
  }

  const size_t fbase = (size_t)bh * 64 + w * 16 + fg * 4;
#pragma unroll
  for (int e = 0; e < 4; ++e)
#pragma unroll
    for (int r = 0; r < 4; ++r)
      atomicAdd(&KVT[(fbase + r) * 64 + e * 16 + fr], acc[e][r]);
}

// ---------------------------------------------------------------- attention output (proven)
__global__ __launch_bounds__(256) void attn_out(const unsigned short* __restrict__ qkv,
                                                const float* __restrict__ KVT,
                                                const float* __restrict__ ksum,
                                                unsigned short* __restrict__ hout) {
  const int bid = blockIdx.x;
  const int nc = bid & 63, bh = bid >> 6;
  const int h = bh & 7, b = bh >> 3;
  const int n0 = nc << 6;
  __shared__ float qs[64][68];
  __shared__ float denp[64][4];
  __shared__ float zl[64];
  __shared__ float kss[64];
  const int t = threadIdx.x;

#pragma unroll
  for (int half = 0; half < 2; half++) {
    const int row = (t >> 3) + half * 32;
    const int e0 = (t & 7) * 8;
    const unsigned short* srcq = qkv + (size_t)(b * N_SEQ + n0 + row) * QKVN + h * E_ + e0;
    short8 raw = *(const short8*)srcq;
#pragma unroll
    for (int i = 0; i < 8; i++) qs[row][e0 + i] = bf2f((unsigned short)raw[i]);
  }
  if (t < 64) kss[t] = ksum[bh * 64 + t];
  __syncthreads();

  {
    const int r = t >> 2, qp = t & 3;
    float s = 0.f;
#pragma unroll
    for (int e = 0; e < 16; e++) s = fmaf(qs[r][qp * 16 + e], kss[qp * 16 + e], s);
    denp[r][qp] = s;
  }
  __syncthreads();
  if (t < 64) zl[t] = 1.0f / (denp[t][0] + denp[t][1] + denp[t][2] + denp[t][3] + 1e-6f);
  __syncthreads();

  const int f = t & 63, rg = t >> 6;
  float kvc[64];
  const float* kvp = KVT + (size_t)bh * 4096 + (size_t)f * 64;
#pragma unroll
  for (int i = 0; i < 16; i++) {
    float4 v4 = *(const float4*)(kvp + i * 4);
    kvc[4 * i] = v4.x; kvc[4 * i + 1] = v4.y; kvc[4 * i + 2] = v4.z; kvc[4 * i + 3] = v4.w;
  }
#pragma unroll
  for (int i = 0; i < 16; i++) {
    const int row = rg * 16 + i;
    float a = 0.f;
#pragma unroll
    for (int e4 = 0; e4 < 16; e4++) {
      float4 qv = *(const float4*)&qs[row][e4 * 4];
      a = fmaf(qv.x, kvc[4 * e4 + 0], a);
      a = fmaf(qv.y, kvc[4 * e4 + 1], a);
      a = fmaf(qv.z, kvc[4 * e4 + 2], a);
      a = fmaf(qv.w, kvc[4 * e4 + 3], a);
    }
    const float val = a * zl[row];
    hout[(size_t)(b * N_SEQ + n0 + row) * C_ + h * E_ + f] = f2bf(val);
  }
}

// ---------------------------------------------------------------- launcher
extern "C" void kernel_launch(void* const* d_in, const int* in_sizes, int n_in,
                              void* d_out, int out_size, void* d_ws, size_t ws_size,
                              hipStream_t stream) {
  const float* x  = (const float*)d_in[0];
  const float* wq = (const float*)d_in[1];
  const float* wp = (const float*)d_in[2];
  const float* bp = (const float*)d_in[3];
  float* out = (float*)d_out;

  char* ws = (char*)d_ws;
  const size_t SZ_HOUT = (size_t)M_TOT * C_ * 2;      //  67108864
  const size_t SZ_QKV  = (size_t)M_TOT * QKVN * 2;    // 201326592
  const size_t SZ_WQ   = (size_t)QKVN * C_ * 2;       //   1572864
  const size_t SZ_WP   = (size_t)C_ * C_ * 2;         //    524288
  const size_t SZ_KVT  = (size_t)128 * 64 * 64 * 4;   //   2097152
  unsigned short* hout   = (unsigned short*)(ws);
  unsigned short* qkv_bf = (unsigned short*)(ws + SZ_HOUT);
  unsigned short* wq_bf  = (unsigned short*)(ws + SZ_HOUT + SZ_QKV);
  unsigned short* wp_bf  = (unsigned short*)(ws + SZ_HOUT + SZ_QKV + SZ_WQ);
  float* KVT   = (float*)(ws + SZ_HOUT + SZ_QKV + SZ_WQ + SZ_WP);
  float* ksumb = (float*)(ws + SZ_HOUT + SZ_QKV + SZ_WQ + SZ_WP + SZ_KVT);

  // small setup dispatch: weight cvt + zero KVT/ksum (x-cvt fused into GEMM1)
  cvt_w<<<1032, 256, 0, stream>>>(wq, wp, wq_bf, wp_bf, KVT);

  gemm_qkv<<<1536, 512, 0, stream>>>(x, wq_bf, qkv_bf, ksumb, 6);
  kv_mfma<<<1024, 256, 0, stream>>>(qkv_bf, KVT);
  attn_out<<<8192, 256, 0, stream>>>(qkv_bf, KVT, ksumb, hout);
  gemm_out<<<512, 512, 0, stream>>>(hout, wp_bf, out, bp, 2);
}

// Round 17
// 345.622 us; speedup vs baseline: 1.0619x; 1.0619x over previous
//
#include <hip/hip_runtime.h>
#include <stdint.h>
#include <stddef.h>

// Problem constants
#define B_    16
#define N_SEQ 4096
#define C_    512
#define H_    8
#define E_    64
#define M_TOT (B_ * N_SEQ)   // 65536
#define QKVN  (3 * C_)       // 1536

typedef __attribute__((ext_vector_type(8))) short short8;
typedef __attribute__((ext_vector_type(4))) short s16x4;
typedef __attribute__((ext_vector_type(4))) float f32x4;

__device__ __forceinline__ unsigned short f2bf(float f) {
  uint32_t u = __builtin_bit_cast(uint32_t, f);
  return (unsigned short)((u + 0x7fffu + ((u >> 16) & 1u)) >> 16);  // RNE
}
__device__ __forceinline__ float bf2f(unsigned short h) {
  uint32_t u = ((uint32_t)h) << 16;
  return __builtin_bit_cast(float, u);
}

// ---------------------------------------------------------------- cvt + zero (one dispatch)
// blocks [0,16384): x f32->bf16; [16384,16768): W_qkv; [16768,16896): W_proj;
// [16896,17416): zero KVT+ksum (532480 f32)
__global__ __launch_bounds__(256) void cvt_all(const float* __restrict__ x,
                                               const float* __restrict__ wq,
                                               const float* __restrict__ wp,
                                               unsigned short* __restrict__ xo,
                                               unsigned short* __restrict__ wqo,
                                               unsigned short* __restrict__ wpo,
                                               float* __restrict__ zbuf) {
  const int bb = blockIdx.x;
  if (bb >= 16896) {
    size_t i = ((size_t)(bb - 16896) * 256 + threadIdx.x) * 4;
    *(float4*)(zbuf + i) = make_float4(0.f, 0.f, 0.f, 0.f);
    return;
  }
  const float* in;
  unsigned short* out;
  size_t base;
  if (bb < 16384)      { in = x;  out = xo;  base = (size_t)bb * 2048; }
  else if (bb < 16768) { in = wq; out = wqo; base = (size_t)(bb - 16384) * 2048; }
  else                 { in = wp; out = wpo; base = (size_t)(bb - 16768) * 2048; }
  size_t i = base + (size_t)threadIdx.x * 8;
  float4 a = *(const float4*)(in + i);
  float4 b = *(const float4*)(in + i + 4);
  short8 o;
  o[0] = (short)f2bf(a.x); o[1] = (short)f2bf(a.y);
  o[2] = (short)f2bf(a.z); o[3] = (short)f2bf(a.w);
  o[4] = (short)f2bf(b.x); o[5] = (short)f2bf(b.y);
  o[6] = (short)f2bf(b.z); o[7] = (short)f2bf(b.w);
  *(short8*)(out + i) = o;
}

#define GLD16(g, l)                                                              \
  __builtin_amdgcn_global_load_lds(                                              \
      (const __attribute__((address_space(1))) void*)(g),                        \
      (__attribute__((address_space(3))) void*)(l), 16, 0, 0)

// ---------------------------------------------------------------- GEMM (C = A * B^T), bf16 in, f32 accum
// R8/R12-verified best: 256x256 tile, BK=64, 8 waves (wave-tile 128x64),
// double-buffered LDS 128 KiB, T2 slot-XOR swizzle (SQ_LDS_BANK_CONFLICT = 0
// measured), setprio around the MFMA cluster, XCD-aware bijective block swizzle.
// MODE 1: qkv epilogue -> bf16 store, relu+0.125 on cols < 1024; ksum for k cols
// MODE 2: f32 store + bias
template <int MODE>
__global__ __launch_bounds__(512, 2) void gemm_bt(
    const unsigned short* __restrict__ A, const unsigned short* __restrict__ Bm,
    void* __restrict__ Cout, const float* __restrict__ bias,
    float* __restrict__ ksum, int M, int N, int NT) {
  const int K = 512;
  __shared__ unsigned short lds[2][2][256 * 64];  // 128 KiB
  const int q8 = gridDim.x >> 3;
  int bid = blockIdx.x;
  bid = (bid & 7) * q8 + (bid >> 3);
  const int mt = bid / NT, nt = bid - mt * NT;
  const int row0 = mt << 8, col0 = nt << 8;
  const int tid = threadIdx.x;
  const int lane = tid & 63, wave = tid >> 6;
  const int wm = wave & 1, wn = wave >> 1;
  const int fr = lane & 15, fg = lane >> 4;

  const int s_row = tid >> 3;
  const int s_slot = (tid & 7) ^ (s_row & 7);
  const unsigned short* gA = A + (size_t)(row0 + s_row) * K + s_slot * 8;
  const unsigned short* gB = Bm + (size_t)(col0 + s_row) * K + s_slot * 8;

  f32x4 acc[8][4] = {};

#define STAGE(kt)                                                        \
  {                                                                      \
    unsigned short* dA = &lds[(kt) & 1][0][tid * 8];                     \
    unsigned short* dB = &lds[(kt) & 1][1][tid * 8];                     \
    _Pragma("unroll")                                                    \
    for (int i = 0; i < 4; i++) {                                        \
      GLD16(gA + (size_t)i * 64 * K + (kt) * 64, dA + i * 4096);         \
      GLD16(gB + (size_t)i * 64 * K + (kt) * 64, dB + i * 4096);         \
    }                                                                    \
  }

  STAGE(0);
  __syncthreads();

  for (int kt = 0; kt < 8; ++kt) {
    if (kt < 7) STAGE(kt + 1);
    const unsigned short* bufA = &lds[kt & 1][0][0];
    const unsigned short* bufB = &lds[kt & 1][1][0];
#pragma unroll
    for (int kk = 0; kk < 2; ++kk) {
      const int sl = ((kk * 4 + fg) ^ (fr & 7)) * 8;
      short8 af[8], bg[4];
#pragma unroll
      for (int m = 0; m < 8; m++)
        af[m] = *(const short8*)&bufA[(wm * 128 + m * 16 + fr) * 64 + sl];
#pragma unroll
      for (int n = 0; n < 4; n++)
        bg[n] = *(const short8*)&bufB[(wn * 64 + n * 16 + fr) * 64 + sl];
      __builtin_amdgcn_s_setprio(1);
#pragma unroll
      for (int m = 0; m < 8; m++)
#pragma unroll
        for (int n = 0; n < 4; n++)
          acc[m][n] = __builtin_amdgcn_mfma_f32_16x16x32_bf16(af[m], bg[n], acc[m][n], 0, 0, 0);
      __builtin_amdgcn_s_setprio(0);
    }
    __syncthreads();
  }
#undef STAGE

  if (MODE == 1) {
    unsigned short* Cq = (unsigned short*)Cout;
    const bool isqk = (col0 < 2 * C_);
    const bool isk = (col0 >= C_) && (col0 < 2 * C_);
    float ksp[4] = {0.f, 0.f, 0.f, 0.f};
#pragma unroll
    for (int m = 0; m < 8; m++) {
      const int r0 = row0 + wm * 128 + m * 16 + fg * 4;
#pragma unroll
      for (int n = 0; n < 4; n++) {
        const int c = col0 + wn * 64 + n * 16 + fr;
#pragma unroll
        for (int r = 0; r < 4; r++) {
          float v = acc[m][n][r];
          if (isqk) v = fmaxf(v, 0.0f) + 0.125f;   // relu + E^-0.5
          if (isk) ksp[n] += v;
          Cq[(size_t)(r0 + r) * N + c] = f2bf(v);
        }
      }
    }
    if (isk) {
      const int b = row0 >> 12;
#pragma unroll
      for (int n = 0; n < 4; n++) {
        float s = ksp[n];
        s += __shfl_xor(s, 16, 64);
        s += __shfl_xor(s, 32, 64);
        if (lane < 16) {
          const int cc = col0 + wn * 64 + n * 16 + lane - C_;  // 0..511
          atomicAdd(&ksum[(size_t)((b << 3) + (cc >> 6)) * 64 + (cc & 63)], s);
        }
      }
    }
  } else {
    float* Cf = (float*)Cout;
#pragma unroll
    for (int m = 0; m < 8; m++) {
      const int r0 = row0 + wm * 128 + m * 16 + fg * 4;
#pragma unroll
      for (int n = 0; n < 4; n++) {
        const int c = col0 + wn * 64 + n * 16 + fr;
        const float bb = bias[c];
#pragma unroll
        for (int r = 0; r < 4; r++)
          Cf[(size_t)(r0 + r) * N + c] = acc[m][n][r] + bb;
      }
    }
  }
}

// ---------------------------------------------------------------- KV^T via MFMA (proven)
__global__ __launch_bounds__(256) void kv_mfma(const unsigned short* __restrict__ qkv,
                                               float* __restrict__ KVT) {
  const int bid = blockIdx.x;
  const int ch = bid & 7, bh = bid >> 3;
  const int h = bh & 7, b = bh >> 3;
  const int n0 = ch << 9;
  __shared__ unsigned short ktile[64][68];
  __shared__ unsigned short vtile[64][68];
  const int tid = threadIdx.x;
  const int lane = tid & 63, w = tid >> 6;
  const int fr = lane & 15, fg = lane >> 4;
  const int srow = tid >> 3;
  const int sseg = (tid & 7) << 3;
  const unsigned short* gk = qkv + (size_t)(b * N_SEQ + n0 + srow) * QKVN + C_ + h * E_ + sseg;
  const unsigned short* gv = gk + C_;

  f32x4 acc[4] = {};
  short8 pk0, pk1, pv0, pv1;
  pk0 = *(const short8*)gk;
  pk1 = *(const short8*)(gk + (size_t)32 * QKVN);
  pv0 = *(const short8*)gv;
  pv1 = *(const short8*)(gv + (size_t)32 * QKVN);

  for (int it = 0; it < 8; ++it) {
    {
      s16x4* dk0 = (s16x4*)&ktile[srow][sseg];
      s16x4* dk1 = (s16x4*)&ktile[srow + 32][sseg];
      s16x4* dv0 = (s16x4*)&vtile[srow][sseg];
      s16x4* dv1 = (s16x4*)&vtile[srow + 32][sseg];
      const s16x4* s;
      s = (const s16x4*)&pk0; dk0[0] = s[0]; dk0[1] = s[1];
      s = (const s16x4*)&pk1; dk1[0] = s[0]; dk1[1] = s[1];
      s = (const s16x4*)&pv0; dv0[0] = s[0]; dv0[1] = s[1];
      s = (const s16x4*)&pv1; dv1[0] = s[0]; dv1[1] = s[1];
    }
    __syncthreads();
    if (it < 7) {
      const unsigned short* nk = gk + (size_t)(it + 1) * 64 * QKVN;
      const unsigned short* nv = gv + (size_t)(it + 1) * 64 * QKVN;
      pk0 = *(const short8*)nk;
      pk1 = *(const short8*)(nk + (size_t)32 * QKVN);
      pv0 = *(const short8*)nv;
      pv1 = *(const short8*)(nv + (size_t)32 * QKVN);
    }
#pragma unroll
    for (int ks = 0; ks < 2; ++ks) {
      const int kb = ks * 32;
      short8 av, bk0, bk1, bk2, bk3;
#pragma unroll
      for (int j = 0; j < 8; ++j) {
        const int row = kb + fg * 8 + j;
        av[j]  = (short)vtile[row][w * 16 + fr];
        bk0[j] = (short)ktile[row][fr];
        bk1[j] = (short)ktile[row][16 + fr];
        bk2[j] = (short)ktile[row][32 + fr];
        bk3[j] = (short)ktile[row][48 + fr];
      }
      acc[0] = __builtin_amdgcn_mfma_f32_16x16x32_bf16(av, bk0, acc[0], 0, 0, 0);
      acc[1] = __builtin_amdgcn_mfma_f32_16x16x32_bf16(av, bk1, acc[1], 0, 0, 0);
      acc[2] = __builtin_amdgcn_mfma_f32_16x16x32_bf16(av, bk2, acc[2], 0, 0, 0);
      acc[3] = __builtin_amdgcn_mfma_f32_16x16x32_bf16(av, bk3, acc[3], 0, 0, 0);
    }
    __syncthreads();
  }

  const size_t fbase = (size_t)bh * 64 + w * 16 + fg * 4;
#pragma unroll
  for (int e = 0; e < 4; ++e)
#pragma unroll
    for (int r = 0; r < 4; ++r)
      atomicAdd(&KVT[(fbase + r) * 64 + e * 16 + fr], acc[e][r]);
}

// ---------------------------------------------------------------- attention output (proven)
__global__ __launch_bounds__(256) void attn_out(const unsigned short* __restrict__ qkv,
                                                const float* __restrict__ KVT,
                                                const float* __restrict__ ksum,
                                                unsigned short* __restrict__ hout) {
  const int bid = blockIdx.x;
  const int nc = bid & 63, bh = bid >> 6;
  const int h = bh & 7, b = bh >> 3;
  const int n0 = nc << 6;
  __shared__ float qs[64][68];
  __shared__ float denp[64][4];
  __shared__ float zl[64];
  __shared__ float kss[64];
  const int t = threadIdx.x;

#pragma unroll
  for (int half = 0; half < 2; half++) {
    const int row = (t >> 3) + half * 32;
    const int e0 = (t & 7) * 8;
    const unsigned short* srcq = qkv + (size_t)(b * N_SEQ + n0 + row) * QKVN + h * E_ + e0;
    short8 raw = *(const short8*)srcq;
#pragma unroll
    for (int i = 0; i < 8; i++) qs[row][e0 + i] = bf2f((unsigned short)raw[i]);
  }
  if (t < 64) kss[t] = ksum[bh * 64 + t];
  __syncthreads();

  {
    const int r = t >> 2, qp = t & 3;
    float s = 0.f;
#pragma unroll
    for (int e = 0; e < 16; e++) s = fmaf(qs[r][qp * 16 + e], kss[qp * 16 + e], s);
    denp[r][qp] = s;
  }
  __syncthreads();
  if (t < 64) zl[t] = 1.0f / (denp[t][0] + denp[t][1] + denp[t][2] + denp[t][3] + 1e-6f);
  __syncthreads();

  const int f = t & 63, rg = t >> 6;
  float kvc[64];
  const float* kvp = KVT + (size_t)bh * 4096 + (size_t)f * 64;
#pragma unroll
  for (int i = 0; i < 16; i++) {
    float4 v4 = *(const float4*)(kvp + i * 4);
    kvc[4 * i] = v4.x; kvc[4 * i + 1] = v4.y; kvc[4 * i + 2] = v4.z; kvc[4 * i + 3] = v4.w;
  }
#pragma unroll
  for (int i = 0; i < 16; i++) {
    const int row = rg * 16 + i;
    float a = 0.f;
#pragma unroll
    for (int e4 = 0; e4 < 16; e4++) {
      float4 qv = *(const float4*)&qs[row][e4 * 4];
      a = fmaf(qv.x, kvc[4 * e4 + 0], a);
      a = fmaf(qv.y, kvc[4 * e4 + 1], a);
      a = fmaf(qv.z, kvc[4 * e4 + 2], a);
      a = fmaf(qv.w, kvc[4 * e4 + 3], a);
    }
    const float val = a * zl[row];
    hout[(size_t)(b * N_SEQ + n0 + row) * C_ + h * E_ + f] = f2bf(val);
  }
}

// ---------------------------------------------------------------- launcher
extern "C" void kernel_launch(void* const* d_in, const int* in_sizes, int n_in,
                              void* d_out, int out_size, void* d_ws, size_t ws_size,
                              hipStream_t stream) {
  const float* x  = (const float*)d_in[0];
  const float* wq = (const float*)d_in[1];
  const float* wp = (const float*)d_in[2];
  const float* bp = (const float*)d_in[3];
  float* out = (float*)d_out;

  char* ws = (char*)d_ws;
  const size_t SZ_XBF  = (size_t)M_TOT * C_ * 2;      //  67108864
  const size_t SZ_QKV  = (size_t)M_TOT * QKVN * 2;    // 201326592
  const size_t SZ_WQ   = (size_t)QKVN * C_ * 2;       //   1572864
  const size_t SZ_WP   = (size_t)C_ * C_ * 2;         //    524288
  const size_t SZ_KVT  = (size_t)128 * 64 * 64 * 4;   //   2097152
  unsigned short* x_bf   = (unsigned short*)(ws);
  unsigned short* qkv_bf = (unsigned short*)(ws + SZ_XBF);
  unsigned short* wq_bf  = (unsigned short*)(ws + SZ_XBF + SZ_QKV);
  unsigned short* wp_bf  = (unsigned short*)(ws + SZ_XBF + SZ_QKV + SZ_WQ);
  float* KVT   = (float*)(ws + SZ_XBF + SZ_QKV + SZ_WQ + SZ_WP);
  float* ksumb = (float*)(ws + SZ_XBF + SZ_QKV + SZ_WQ + SZ_WP + SZ_KVT);
  unsigned short* hout = x_bf;  // reuse: x_bf dead after GEMM1

  // one setup dispatch: converts x/Wqkv/Wproj and zeroes KVT+ksum
  cvt_all<<<17416, 256, 0, stream>>>(x, wq, wp, x_bf, wq_bf, wp_bf, KVT);

  gemm_bt<1><<<1536, 512, 0, stream>>>(x_bf, wq_bf, qkv_bf, nullptr, ksumb,
                                       M_TOT, QKVN, 6);
  kv_mfma<<<1024, 256, 0, stream>>>(qkv_bf, KVT);
  attn_out<<<8192, 256, 0, stream>>>(qkv_bf, KVT, ksumb, hout);
  gemm_bt<2><<<512, 512, 0, stream>>>(hout, wp_bf, out, bp, nullptr,
                                      M_TOT, C_, 2);
}